// Round 6
// baseline (183.847 us; speedup 1.0000x reference)
//
#include <hip/hip_runtime.h>
#include <hip/hip_bf16.h>

#define H 8
#define D 32
#define HD 256            // H*D floats per edge/node row
#define NEG_SLOPE 0.01f

typedef float f32x4 __attribute__((ext_vector_type(4)));

// ---------------- CSR build ----------------

__global__ void hist_kernel(const int* __restrict__ dst, int E, int* __restrict__ count) {
    int i = blockIdx.x * blockDim.x + threadIdx.x;
    int base = i * 4;
    if (base + 3 < E) {
        int4 d = *reinterpret_cast<const int4*>(dst + base);
        atomicAdd(&count[d.x], 1);
        atomicAdd(&count[d.y], 1);
        atomicAdd(&count[d.z], 1);
        atomicAdd(&count[d.w], 1);
    } else {
        for (int k = base; k < E; ++k) atomicAdd(&count[dst[k]], 1);
    }
}

// One-kernel offset allocation: LDS-scan 256 counts, grab block base via one
// global atomicAdd (CSR segment order need not be monotone in node id),
// emit pack[i]=(start,len) and cursor init.
__global__ void scan_alloc_kernel(const int* __restrict__ count, int n,
                                  int* __restrict__ gcursor,
                                  int2* __restrict__ pack, int* __restrict__ cursor) {
    __shared__ int s[256];
    __shared__ int base_s;
    int t = threadIdx.x;
    int i = blockIdx.x * 256 + t;
    int v = (i < n) ? count[i] : 0;
    s[t] = v;
    __syncthreads();
    for (int off = 1; off < 256; off <<= 1) {
        int x = (t >= off) ? s[t - off] : 0;
        __syncthreads();
        s[t] += x;
        __syncthreads();
    }
    if (t == 255) base_s = atomicAdd(gcursor, s[255]);
    __syncthreads();
    if (i < n) {
        int start = base_s + s[t] - v;   // exclusive within block + block base
        pack[i] = make_int2(start, v);
        cursor[i] = start;
    }
}

__global__ void scatter_kernel(const int* __restrict__ dst, int E,
                               int* __restrict__ cursor, int* __restrict__ csr) {
    int i = blockIdx.x * blockDim.x + threadIdx.x;
    int base = i * 4;
    if (base + 3 < E) {
        int4 d = *reinterpret_cast<const int4*>(dst + base);
        int p0 = atomicAdd(&cursor[d.x], 1); csr[p0] = base;
        int p1 = atomicAdd(&cursor[d.y], 1); csr[p1] = base + 1;
        int p2 = atomicAdd(&cursor[d.z], 1); csr[p2] = base + 2;
        int p3 = atomicAdd(&cursor[d.w], 1); csr[p3] = base + 3;
    } else {
        for (int k = base; k < E; ++k) {
            int p = atomicAdd(&cursor[dst[k]], 1);
            csr[p] = k;
        }
    }
}

// ---------------- fused score + softmax + aggregate + ELU ----------------
// TWO nodes per wave. Lane l owns floats [4l,4l+4) of the 256-float row.
//  - one int4 load fetches both (start,len) descriptors
//  - one csr load serves both nodes: lanes 0-31 gather A's edge ids,
//    lanes 32-63 gather B's; per-edge id via __shfl broadcast
//  - main loop interleaves 4 A-rows + 4 B-rows static prefetch (8KB in flight)
//  - deg>32 handled by rare full-wave tail loop
//  - nontemporal feat loads / out stores
__global__ void aggregate_kernel(const float* __restrict__ feat,
                                 const float* __restrict__ attn_r,
                                 const int* __restrict__ csr,
                                 const int2* __restrict__ pack,
                                 float* __restrict__ out, int N, int E) {
    int wid  = (blockIdx.x * blockDim.x + threadIdx.x) >> 6;   // wave id = node pair
    int lane = threadIdx.x & 63;
    int nA = wid * 2;
    int nB = nA + 1;
    if (nA >= N) return;

    f32x4 ar = reinterpret_cast<const f32x4*>(attn_r)[lane];

    int4 se = reinterpret_cast<const int4*>(pack)[wid];   // (startA,lenA,startB,lenB)
    int startA = se.x, lenA = se.y;
    int startB = se.z, lenB = se.w;
    if (nB >= N) { startB = 0; lenB = 0; }

    // one coalesced csr load for both halves (covers first 32 edges of each)
    int half  = lane >> 5;
    int hl    = lane & 31;
    int st_h  = half ? startB : startA;
    int ln_h  = half ? lenB   : lenA;
    int off_h = (ln_h > 0) ? min(hl, ln_h - 1) : 0;
    int eidx  = csr[min(st_h + off_h, E - 1)];

    f32x4 accA = (f32x4)(0.f), accB = (f32x4)(0.f);
    float denA = 0.f, denB = 0.f;

    const f32x4* featv = reinterpret_cast<const f32x4*>(feat);

#define PROC(fi, accX, denX) { \
    float part = fi.x * ar.x + fi.y * ar.y + fi.z * ar.z + fi.w * ar.w; \
    part += __shfl_xor(part, 1); \
    part += __shfl_xor(part, 2); \
    part += __shfl_xor(part, 4); \
    float el  = (part > 0.f) ? part : NEG_SLOPE * part; \
    float num = __expf(el); \
    denX += num; \
    accX.x += num * fi.x; accX.y += num * fi.y; \
    accX.z += num * fi.z; accX.w += num * fi.w; }

    int lenC = min(max(lenA, lenB), 32);
    for (int c = 0; c < lenC; c += 4) {
        f32x4 a0, a1, a2, a3, b0, b1, b2, b3;
        // issue up to 8 row loads (A then B) into named registers
        if (lenA > c    ) { int e = __shfl(eidx, c    ); a0 = __builtin_nontemporal_load(&featv[(size_t)e * 64 + lane]); }
        if (lenA > c + 1) { int e = __shfl(eidx, c + 1); a1 = __builtin_nontemporal_load(&featv[(size_t)e * 64 + lane]); }
        if (lenA > c + 2) { int e = __shfl(eidx, c + 2); a2 = __builtin_nontemporal_load(&featv[(size_t)e * 64 + lane]); }
        if (lenA > c + 3) { int e = __shfl(eidx, c + 3); a3 = __builtin_nontemporal_load(&featv[(size_t)e * 64 + lane]); }
        if (lenB > c    ) { int e = __shfl(eidx, 32 + c    ); b0 = __builtin_nontemporal_load(&featv[(size_t)e * 64 + lane]); }
        if (lenB > c + 1) { int e = __shfl(eidx, 32 + c + 1); b1 = __builtin_nontemporal_load(&featv[(size_t)e * 64 + lane]); }
        if (lenB > c + 2) { int e = __shfl(eidx, 32 + c + 2); b2 = __builtin_nontemporal_load(&featv[(size_t)e * 64 + lane]); }
        if (lenB > c + 3) { int e = __shfl(eidx, 32 + c + 3); b3 = __builtin_nontemporal_load(&featv[(size_t)e * 64 + lane]); }
        if (lenA > c    ) PROC(a0, accA, denA)
        if (lenA > c + 1) PROC(a1, accA, denA)
        if (lenA > c + 2) PROC(a2, accA, denA)
        if (lenA > c + 3) PROC(a3, accA, denA)
        if (lenB > c    ) PROC(b0, accB, denB)
        if (lenB > c + 1) PROC(b1, accB, denB)
        if (lenB > c + 2) PROC(b2, accB, denB)
        if (lenB > c + 3) PROC(b3, accB, denB)
    }

    // rare tails for degree > 32 (full-wave, one row at a time)
    for (int k = 32; k < lenA; ++k) {
        int e = csr[startA + k];
        f32x4 f = __builtin_nontemporal_load(&featv[(size_t)e * 64 + lane]);
        PROC(f, accA, denA)
    }
    for (int k = 32; k < lenB; ++k) {
        int e = csr[startB + k];
        f32x4 f = __builtin_nontemporal_load(&featv[(size_t)e * 64 + lane]);
        PROC(f, accB, denB)
    }
#undef PROC

#define FINISH(accX, denX, node) { \
    float inv = ((node) < N && denX > 0.f) ? (1.0f / denX) : 0.0f; \
    f32x4 o; \
    o.x = accX.x * inv; o.y = accX.y * inv; \
    o.z = accX.z * inv; o.w = accX.w * inv; \
    o.x = (o.x > 0.f) ? o.x : expm1f(o.x); \
    o.y = (o.y > 0.f) ? o.y : expm1f(o.y); \
    o.z = (o.z > 0.f) ? o.z : expm1f(o.z); \
    o.w = (o.w > 0.f) ? o.w : expm1f(o.w); \
    if ((node) < N) \
        __builtin_nontemporal_store(o, &reinterpret_cast<f32x4*>(out)[(size_t)(node) * 64 + lane]); }

    FINISH(accA, denA, nA)
    FINISH(accB, denB, nB)
#undef FINISH
}

// ---------------- launch ----------------

extern "C" void kernel_launch(void* const* d_in, const int* in_sizes, int n_in,
                              void* d_out, int out_size, void* d_ws, size_t ws_size,
                              hipStream_t stream) {
    const float* feat   = (const float*)d_in[0];
    const float* attn_r = (const float*)d_in[1];
    const int*   dst    = (const int*)d_in[2];
    float*       out    = (float*)d_out;

    const int E = in_sizes[0] / HD;   // 500000
    const int N = out_size / HD;      // 100000
    const int NB = (N + 255) / 256;

    // workspace layout: pack(int2[N+2]) | count[N] | gcursor[1] | cursor[N] | csr[E]
    int2* pack    = (int2*)d_ws;                    // 16B-aligned at ws base
    int*  count   = (int*)(pack + (N + 2));
    int*  gcursor = count + N;
    int*  cursor  = gcursor + 1;
    int*  csr     = cursor + N;
    // total ~= 3.6 MB

    // zero count + gcursor in one memset (adjacent)
    (void)hipMemsetAsync(count, 0, (size_t)(N + 1) * sizeof(int), stream);

    const int E4 = (E + 3) / 4;
    hist_kernel<<<(E4 + 255) / 256, 256, 0, stream>>>(dst, E, count);
    scan_alloc_kernel<<<NB, 256, 0, stream>>>(count, N, gcursor, pack, cursor);
    scatter_kernel<<<(E4 + 255) / 256, 256, 0, stream>>>(dst, E, cursor, csr);

    const int nwaves = (N + 1) / 2;              // one wave per node pair
    const int nblocks = (nwaves + 3) / 4;        // 4 waves per 256-thread block
    aggregate_kernel<<<nblocks, 256, 0, stream>>>(feat, attn_r, csr, pack, out, N, E);
}

// Round 7
// 173.092 us; speedup vs baseline: 1.0621x; 1.0621x over previous
//
#include <hip/hip_runtime.h>
#include <hip/hip_bf16.h>

#define H 8
#define D 32
#define HD 256            // H*D floats per edge/node row
#define NEG_SLOPE 0.01f

typedef float f32x4 __attribute__((ext_vector_type(4)));

// ---------------- CSR build ----------------

__global__ void hist_kernel(const int* __restrict__ dst, int E, int* __restrict__ count) {
    int i = blockIdx.x * blockDim.x + threadIdx.x;
    int base = i * 4;
    if (base + 3 < E) {
        int4 d = *reinterpret_cast<const int4*>(dst + base);
        atomicAdd(&count[d.x], 1);
        atomicAdd(&count[d.y], 1);
        atomicAdd(&count[d.z], 1);
        atomicAdd(&count[d.w], 1);
    } else {
        for (int k = base; k < E; ++k) atomicAdd(&count[dst[k]], 1);
    }
}

// One-kernel offset allocation: LDS-scan 256 counts, grab block base via one
// global atomicAdd (CSR segment order need not be monotone in node id),
// emit pack[i]=(start,len) and cursor init.
__global__ void scan_alloc_kernel(const int* __restrict__ count, int n,
                                  int* __restrict__ gcursor,
                                  int2* __restrict__ pack, int* __restrict__ cursor) {
    __shared__ int s[256];
    __shared__ int base_s;
    int t = threadIdx.x;
    int i = blockIdx.x * 256 + t;
    int v = (i < n) ? count[i] : 0;
    s[t] = v;
    __syncthreads();
    for (int off = 1; off < 256; off <<= 1) {
        int x = (t >= off) ? s[t - off] : 0;
        __syncthreads();
        s[t] += x;
        __syncthreads();
    }
    if (t == 255) base_s = atomicAdd(gcursor, s[255]);
    __syncthreads();
    if (i < n) {
        int start = base_s + s[t] - v;   // exclusive within block + block base
        pack[i] = make_int2(start, v);
        cursor[i] = start;
    }
}

__global__ void scatter_kernel(const int* __restrict__ dst, int E,
                               int* __restrict__ cursor, int* __restrict__ csr) {
    int i = blockIdx.x * blockDim.x + threadIdx.x;
    int base = i * 4;
    if (base + 3 < E) {
        int4 d = *reinterpret_cast<const int4*>(dst + base);
        int p0 = atomicAdd(&cursor[d.x], 1); csr[p0] = base;
        int p1 = atomicAdd(&cursor[d.y], 1); csr[p1] = base + 1;
        int p2 = atomicAdd(&cursor[d.z], 1); csr[p2] = base + 2;
        int p3 = atomicAdd(&cursor[d.w], 1); csr[p3] = base + 3;
    } else {
        for (int k = base; k < E; ++k) {
            int p = atomicAdd(&cursor[dst[k]], 1);
            csr[p] = k;
        }
    }
}

// ---------------- fused score + softmax + aggregate + ELU ----------------
// 128-thread blocks = 2 waves; wave w handles node 2*blockIdx+w (one node
// per wave, as in the best-so-far R4 structure). Both descriptors come from
// ONE block-uniform int4 load -> s_load_dwordx4 (no vector L2 round trip).
// Lane l owns floats [4l,4l+4) of the 256-float row -> head = l/8.
//  - all edge indices via ONE coalesced load (csr[start+lane]), shfl-broadcast
//  - static depth-8 batches: 8 row loads into named regs, then process 8
//    (zero rotation moves, 8 KB in flight per wave)
//  - nontemporal feat loads / out stores (each row touched exactly once)
__global__ void aggregate_kernel(const float* __restrict__ feat,
                                 const float* __restrict__ attn_r,
                                 const int* __restrict__ csr,
                                 const int2* __restrict__ pack,
                                 float* __restrict__ out, int N) {
    int b    = blockIdx.x;
    int w    = threadIdx.x >> 6;          // wave in block: 0 or 1
    int lane = threadIdx.x & 63;
    int node = b * 2 + w;

    // block-uniform descriptor load (covers both waves' nodes)
    int4 se = reinterpret_cast<const int4*>(pack)[b];
    int start = w ? se.z : se.x;
    int len   = w ? se.w : se.y;
    if (node >= N) return;

    f32x4 ar = reinterpret_cast<const f32x4*>(attn_r)[lane];

    f32x4 acc = (f32x4)(0.f);
    float den = 0.f;

    const f32x4* featv = reinterpret_cast<const f32x4*>(feat);

#define LOADF(i, fi) if (r > (i)) { int e = __shfl(eidx, c + (i)); \
    fi = __builtin_nontemporal_load(&featv[(size_t)e * 64 + lane]); }
#define PROC(fi) { \
    float part = fi.x * ar.x + fi.y * ar.y + fi.z * ar.z + fi.w * ar.w; \
    part += __shfl_xor(part, 1); \
    part += __shfl_xor(part, 2); \
    part += __shfl_xor(part, 4); \
    float el  = (part > 0.f) ? part : NEG_SLOPE * part; \
    float num = __expf(el); \
    den   += num; \
    acc.x += num * fi.x; acc.y += num * fi.y; \
    acc.z += num * fi.z; acc.w += num * fi.w; }

    for (int base = 0; base < len; base += 64) {
        int rem = min(64, len - base);
        // one coalesced load grabs up to 64 edge indices for this node
        int eidx = csr[start + base + min(lane, rem - 1)];

        for (int c = 0; c < rem; c += 8) {
            int r = rem - c;          // wave-uniform
            f32x4 f0, f1, f2, f3, f4, f5, f6, f7;
            { int e = __shfl(eidx, c); f0 = __builtin_nontemporal_load(&featv[(size_t)e * 64 + lane]); }
            LOADF(1, f1) LOADF(2, f2) LOADF(3, f3)
            LOADF(4, f4) LOADF(5, f5) LOADF(6, f6) LOADF(7, f7)
            PROC(f0)
            if (r > 1) PROC(f1)
            if (r > 2) PROC(f2)
            if (r > 3) PROC(f3)
            if (r > 4) PROC(f4)
            if (r > 5) PROC(f5)
            if (r > 6) PROC(f6)
            if (r > 7) PROC(f7)
        }
    }
#undef LOADF
#undef PROC

    float inv = (len > 0) ? (1.0f / den) : 0.0f;  // zero-degree node -> out 0
    f32x4 o;
    o.x = acc.x * inv;
    o.y = acc.y * inv;
    o.z = acc.z * inv;
    o.w = acc.w * inv;
    // ELU
    o.x = (o.x > 0.f) ? o.x : expm1f(o.x);
    o.y = (o.y > 0.f) ? o.y : expm1f(o.y);
    o.z = (o.z > 0.f) ? o.z : expm1f(o.z);
    o.w = (o.w > 0.f) ? o.w : expm1f(o.w);
    __builtin_nontemporal_store(o, &reinterpret_cast<f32x4*>(out)[(size_t)node * 64 + lane]);
}

// ---------------- launch ----------------

extern "C" void kernel_launch(void* const* d_in, const int* in_sizes, int n_in,
                              void* d_out, int out_size, void* d_ws, size_t ws_size,
                              hipStream_t stream) {
    const float* feat   = (const float*)d_in[0];
    const float* attn_r = (const float*)d_in[1];
    const int*   dst    = (const int*)d_in[2];
    float*       out    = (float*)d_out;

    const int E = in_sizes[0] / HD;   // 500000
    const int N = out_size / HD;      // 100000
    const int NB = (N + 255) / 256;

    // workspace layout: pack(int2[N+2]) | count[N] | gcursor[1] | cursor[N] | csr[E]
    int2* pack    = (int2*)d_ws;                    // 16B-aligned at ws base
    int*  count   = (int*)(pack + (N + 2));
    int*  gcursor = count + N;
    int*  cursor  = gcursor + 1;
    int*  csr     = cursor + N;
    // total ~= 3.6 MB

    // zero count + gcursor in one memset (adjacent)
    (void)hipMemsetAsync(count, 0, (size_t)(N + 1) * sizeof(int), stream);

    const int E4 = (E + 3) / 4;
    hist_kernel<<<(E4 + 255) / 256, 256, 0, stream>>>(dst, E, count);
    scan_alloc_kernel<<<NB, 256, 0, stream>>>(count, N, gcursor, pack, cursor);
    scatter_kernel<<<(E4 + 255) / 256, 256, 0, stream>>>(dst, E, cursor, csr);

    const int nblocks = (N + 1) / 2;    // 2 nodes (2 waves) per 128-thread block
    aggregate_kernel<<<nblocks, 128, 0, stream>>>(feat, attn_r, csr, pack, out, N);
}